// Round 1
// baseline (1357.898 us; speedup 1.0000x reference)
//
#include <hip/hip_runtime.h>

typedef __bf16 bf16x8 __attribute__((ext_vector_type(8)));
typedef float f32x4 __attribute__((ext_vector_type(4)));
typedef unsigned short ushort4v __attribute__((ext_vector_type(4)));

__device__ __forceinline__ unsigned short f2bf(float f) {
  unsigned int u = __builtin_bit_cast(unsigned int, f);
  u += 0x7FFFu + ((u >> 16) & 1u);   // round-to-nearest-even
  return (unsigned short)(u >> 16);
}

// ---- cast x (f32 -> bf16), vectorized ----
__global__ __launch_bounds__(256) void cast_x_kernel(const float* __restrict__ in,
                                                     unsigned short* __restrict__ out, int nvec) {
  int stride = gridDim.x * blockDim.x;
  for (int i = blockIdx.x * blockDim.x + threadIdx.x; i < nvec; i += stride) {
    float4 v = ((const float4*)in)[i];
    ushort4v o = { f2bf(v.x), f2bf(v.y), f2bf(v.z), f2bf(v.w) };
    ((ushort4v*)out)[i] = o;
  }
}

// ---- w [K][Cin][Cout] f32 -> wT [K][Cout][Cin] bf16 ----
__global__ __launch_bounds__(256) void wcast_kernel(const float* __restrict__ w,
                                                    unsigned short* __restrict__ wT, int total) {
  int i = blockIdx.x * blockDim.x + threadIdx.x;
  if (i >= total) return;
  int k = i >> 14, rem = i & 16383;
  int d = rem >> 7, c = rem & 127;          // out index: [k][d][c]
  wT[i] = f2bf(w[(k << 14) + (c << 7) + d]);
}

// ---- sparse conv: gather -> MFMA GEMM -> scatter-add (atomics) ----
// grid: (ceil(M/128), K), block 256 (4 waves). LDS: 32KB x-tile + 32KB w-tile, XOR-swizzled.
__global__ __launch_bounds__(256) void spconv_mfma(
    const unsigned short* __restrict__ xb, const unsigned short* __restrict__ wT,
    const int* __restrict__ iin, const int* __restrict__ iout,
    float* __restrict__ out, int M)
{
  __shared__ unsigned short xs[128 * 128];
  __shared__ unsigned short wsm[128 * 128];
  const int k = blockIdx.y;
  const int r0 = blockIdx.x * 128;
  const int t = threadIdx.x;

  // stage wT[k] (bf16 [cout][cin]) into LDS, swizzled
  {
    const char* wk = (const char*)(wT + ((size_t)k << 14));
    #pragma unroll
    for (int j = 0; j < 8; ++j) {
      int byte = (j * 256 + t) * 16;
      int swz = byte ^ (((byte >> 8) & 7) << 4);
      *(uint4*)((char*)wsm + swz) = *(const uint4*)(wk + byte);
    }
  }
  // gather 128 rows of x (bf16) into LDS, swizzled; 2 threads per row
  {
    int row = t >> 1, half = t & 1;
    int r = r0 + row;
    int idx = 0;
    if (r < M) idx = iin[k * M + r];
    const char* src = (const char*)(xb + ((size_t)idx << 7) + half * 64);
    #pragma unroll
    for (int j = 0; j < 8; ++j) {
      int byte = row * 256 + half * 128 + j * 16;
      int swz = byte ^ (((byte >> 8) & 7) << 4);
      *(uint4*)((char*)xs + swz) = *(const uint4*)(src + j * 16);
    }
  }
  __syncthreads();

  const int wv = t >> 6, l = t & 63;
  const int lrow = l & 15;
  const int kb = ((l >> 4) * 8) * 2;   // byte offset of this lane's k-group within a row

  f32x4 acc[2][8];
  #pragma unroll
  for (int a = 0; a < 2; ++a)
    #pragma unroll
    for (int b = 0; b < 8; ++b)
      acc[a][b] = (f32x4){0.f, 0.f, 0.f, 0.f};

  #pragma unroll
  for (int kk = 0; kk < 4; ++kk) {
    int kbyte = kk * 64 + kb;
    bf16x8 af[2];
    #pragma unroll
    for (int rt = 0; rt < 2; ++rt) {
      int row = wv * 32 + rt * 16 + lrow;
      int byte = row * 256 + kbyte;
      af[rt] = *(const bf16x8*)((const char*)xs + (byte ^ ((row & 7) << 4)));
    }
    #pragma unroll
    for (int ct = 0; ct < 8; ++ct) {
      int crow = ct * 16 + lrow;
      int byte = crow * 256 + kbyte;
      bf16x8 bfr = *(const bf16x8*)((const char*)wsm + (byte ^ ((crow & 7) << 4)));
      acc[0][ct] = __builtin_amdgcn_mfma_f32_16x16x32_bf16(af[0], bfr, acc[0][ct], 0, 0, 0);
      acc[1][ct] = __builtin_amdgcn_mfma_f32_16x16x32_bf16(af[1], bfr, acc[1][ct], 0, 0, 0);
    }
  }

  // scatter-add: C layout col=lane&15, row=(lane>>4)*4+reg (m89-verified)
  const int rbase = (l >> 4) * 4;
  #pragma unroll
  for (int rt = 0; rt < 2; ++rt) {
    #pragma unroll
    for (int i = 0; i < 4; ++i) {
      int prow = wv * 32 + rt * 16 + rbase + i;
      int r = r0 + prow;
      if (r < M) {
        int orow = iout[k * M + r];
        float* dst = out + ((size_t)orow << 7) + lrow;
        #pragma unroll
        for (int ct = 0; ct < 8; ++ct)
          atomicAdd(dst + ct * 16, acc[rt][ct][i]);
      }
    }
  }
}

// ---- BN stats: per-channel sum and sumsq ----
__global__ __launch_bounds__(256) void bn_stats_kernel(const float* __restrict__ in,
                                                       float* __restrict__ st, int N) {
  int c = threadIdx.x & 127;
  int rh = threadIdx.x >> 7;
  float s = 0.f, s2 = 0.f;
  for (int r = blockIdx.x * 2 + rh; r < N; r += gridDim.x * 2) {
    float v = in[((size_t)r << 7) + c];
    s += v; s2 += v * v;
  }
  atomicAdd(&st[c], s);
  atomicAdd(&st[128 + c], s2);
}

// ---- BN + ReLU -> bf16 (input to conv2) ----
__global__ __launch_bounds__(256) void bn_relu_bf16_kernel(const float* __restrict__ in,
    const float* __restrict__ st, const float* __restrict__ gamma, const float* __restrict__ beta,
    unsigned short* __restrict__ out, int nvec, float invN)
{
  int stride = gridDim.x * blockDim.x;
  for (int i = blockIdx.x * blockDim.x + threadIdx.x; i < nvec; i += stride) {
    int cb = (i & 31) * 4;
    float4 v = ((const float4*)in)[i];
    float vv[4] = {v.x, v.y, v.z, v.w};
    ushort4v o;
    #pragma unroll
    for (int j = 0; j < 4; ++j) {
      int c = cb + j;
      float mean = st[c] * invN;
      float var = st[128 + c] * invN - mean * mean;
      float y = (vv[j] - mean) * rsqrtf(var + 1e-5f) * gamma[c] + beta[c];
      o[j] = f2bf(fmaxf(y, 0.f));
    }
    ((ushort4v*)out)[i] = o;
  }
}

// ---- BN + residual + ReLU -> f32 output ----
__global__ __launch_bounds__(256) void bn_add_relu_kernel(const float* __restrict__ in,
    const float* __restrict__ st, const float* __restrict__ gamma, const float* __restrict__ beta,
    const float* __restrict__ resid, float* __restrict__ out, int nvec, float invN)
{
  int stride = gridDim.x * blockDim.x;
  for (int i = blockIdx.x * blockDim.x + threadIdx.x; i < nvec; i += stride) {
    int cb = (i & 31) * 4;
    float4 v = ((const float4*)in)[i];
    float4 rz = ((const float4*)resid)[i];
    float vv[4] = {v.x, v.y, v.z, v.w};
    float rr[4] = {rz.x, rz.y, rz.z, rz.w};
    float ov[4];
    #pragma unroll
    for (int j = 0; j < 4; ++j) {
      int c = cb + j;
      float mean = st[c] * invN;
      float var = st[128 + c] * invN - mean * mean;
      float y = (vv[j] - mean) * rsqrtf(var + 1e-5f) * gamma[c] + beta[c] + rr[j];
      ov[j] = fmaxf(y, 0.f);
    }
    float4 o; o.x = ov[0]; o.y = ov[1]; o.z = ov[2]; o.w = ov[3];
    ((float4*)out)[i] = o;
  }
}

extern "C" void kernel_launch(void* const* d_in, const int* in_sizes, int n_in,
                              void* d_out, int out_size, void* d_ws, size_t ws_size,
                              hipStream_t stream) {
  const float* x  = (const float*)d_in[0];
  const float* w1 = (const float*)d_in[1];
  const float* g1 = (const float*)d_in[2];
  const float* b1 = (const float*)d_in[3];
  const float* w2 = (const float*)d_in[4];
  const float* g2 = (const float*)d_in[5];
  const float* b2 = (const float*)d_in[6];
  const int* iin  = (const int*)d_in[7];
  const int* iout = (const int*)d_in[8];

  const int C = 128;
  const int N = in_sizes[0] / C;          // 100000
  const int K = in_sizes[1] / (C * C);    // 27
  const int M = in_sizes[7] / K;          // 50000
  const size_t nc = (size_t)N * C;

  char* ws = (char*)d_ws;
  unsigned short* xb  = (unsigned short*)ws;               // nc bf16 (reused as y_bf16 later)
  unsigned short* w1T = (unsigned short*)(ws + nc * 2);
  unsigned short* w2T = w1T + (size_t)K * C * C;
  float* acc   = (float*)(ws + nc * 2 + (size_t)K * C * C * 4);
  float* stats = acc + nc;                                  // 512 floats (BN1 + BN2)

  const int nvec = (int)(nc / 4);
  const float invN = 1.0f / (float)N;
  const int wtot = K * C * C;

  hipMemsetAsync(acc, 0, nc * 4, stream);
  hipMemsetAsync(stats, 0, 512 * 4, stream);
  cast_x_kernel<<<2048, 256, 0, stream>>>(x, xb, nvec);
  wcast_kernel<<<(wtot + 255) / 256, 256, 0, stream>>>(w1, w1T, wtot);
  wcast_kernel<<<(wtot + 255) / 256, 256, 0, stream>>>(w2, w2T, wtot);

  dim3 cgrid((M + 127) / 128, K);
  // conv1 -> acc
  spconv_mfma<<<cgrid, 256, 0, stream>>>(xb, w1T, iin, iout, acc, M);
  bn_stats_kernel<<<512, 256, 0, stream>>>(acc, stats, N);
  // BN1 + ReLU -> bf16 (overwrites xb; conv1 already consumed it)
  bn_relu_bf16_kernel<<<2048, 256, 0, stream>>>(acc, stats, g1, b1, xb, nvec, invN);
  // conv2 -> acc (re-zeroed)
  hipMemsetAsync(acc, 0, nc * 4, stream);
  spconv_mfma<<<cgrid, 256, 0, stream>>>(xb, w2T, iin, iout, acc, M);
  bn_stats_kernel<<<512, 256, 0, stream>>>(acc, stats + 256, N);
  // BN2 + residual + ReLU -> f32 out
  bn_add_relu_kernel<<<2048, 256, 0, stream>>>(acc, stats + 256, g2, b2, x, (float*)d_out, nvec, invN);
}